// Round 4
// baseline (1451.498 us; speedup 1.0000x reference)
//
#include <hip/hip_runtime.h>

#define DIM 128
#define BINSHIFT 7
#define BINSZ 128          // nodes per bin
#define BCAP 2560          // edges capacity per bin: Poisson(2048)+11sigma
#define EPB 8192           // edges per binning block

typedef __attribute__((ext_vector_type(8))) short bf16x8;
typedef __attribute__((ext_vector_type(4))) float f32x4;

__device__ inline unsigned short f2b(float f) {
    unsigned u = __builtin_bit_cast(unsigned, f);
    unsigned r = (u + 0x7FFFu + ((u >> 16) & 1u)) >> 16;
    return (unsigned short)r;
}
__device__ inline float b2f(unsigned short h) {
    unsigned u = ((unsigned)h) << 16;
    return __builtin_bit_cast(float, u);
}

// ---------------------------------------------------------------- gcur[b] = b*BCAP
__global__ __launch_bounds__(256)
void init_gcur(unsigned* __restrict__ gcur, int nbins)
{
    int i = blockIdx.x * 256 + threadIdx.x;
    if (i < nbins) gcur[i] = (unsigned)i * BCAP;
}

// ---------------------------------------------------------------- x (fp32) -> xb (bf16)
__global__ __launch_bounds__(256)
void x_to_bf16(const float* __restrict__ x, unsigned short* __restrict__ xb, int n8)
{
    int i = blockIdx.x * 256 + threadIdx.x;
    if (i >= n8) return;
    float4 a = ((const float4*)x)[i * 2];
    float4 b = ((const float4*)x)[i * 2 + 1];
    bf16x8 o;
    o[0] = (short)f2b(a.x); o[1] = (short)f2b(a.y); o[2] = (short)f2b(a.z); o[3] = (short)f2b(a.w);
    o[4] = (short)f2b(b.x); o[5] = (short)f2b(b.y); o[6] = (short)f2b(b.z); o[7] = (short)f2b(b.w);
    ((bf16x8*)xb)[i] = o;
}

// ---------------------------------------------------------------- bin edges by dst>>7, packed (dstlow<<17)|src
__global__ __launch_bounds__(1024)
void bin_edges(const int* __restrict__ src, const int* __restrict__ dst,
               unsigned* __restrict__ gcur, unsigned* __restrict__ binned,
               int E, int nbins)
{
    __shared__ unsigned hist[1024];
    __shared__ unsigned base[1024];
    const int t = threadIdx.x;
    const long long bb = (long long)blockIdx.x * EPB;
    if (t < nbins) hist[t] = 0;
    __syncthreads();

    unsigned pk[8], pos[8];
    int bn[8];
    bool ok[8];
    #pragma unroll
    for (int i = 0; i < 8; ++i) {
        long long idx = bb + i * 1024 + t;
        ok[i] = idx < E;
        if (ok[i]) {
            int s = src[idx], d = dst[idx];
            pk[i] = ((unsigned)(d & (BINSZ - 1)) << 17) | (unsigned)s;
            bn[i] = d >> BINSHIFT;
            pos[i] = atomicAdd(&hist[bn[i]], 1u);
        }
    }
    __syncthreads();
    if (t < nbins) base[t] = atomicAdd(&gcur[t], hist[t]);
    __syncthreads();
    #pragma unroll
    for (int i = 0; i < 8; ++i) {
        if (ok[i]) {
            unsigned off = base[bn[i]] + pos[i];
            if (off < (unsigned)(bn[i] + 1) * BCAP) binned[off] = pk[i];
        }
    }
}

// ---------------------------------------------------------------- per-bin aggregate: LDS fp32 accumulate
// block 512 threads, one bin of 128 nodes; acc init = (1+eps)*x[node]; edges add x[src]
__global__ __launch_bounds__(512)
void bin_agg(const unsigned short* __restrict__ xb, const float* __restrict__ epsp,
             const unsigned* __restrict__ gcur, const unsigned* __restrict__ binned,
             unsigned short* __restrict__ h0b, int N)
{
    __shared__ float acc[BINSZ * DIM];   // 64 KB
    const int t = threadIdx.x;
    const int bin = blockIdx.x;
    const int node0 = bin << BINSHIFT;
    const float e = 1.0f + epsp[0];

    #pragma unroll
    for (int i = 0; i < 32; ++i) {
        int flat = i * 512 + t;
        int node = node0 + (flat >> 7);
        float v = 0.f;
        if (node < N) v = e * b2f(xb[(size_t)node * DIM + (flat & 127)]);
        acc[flat] = v;
    }
    __syncthreads();

    int cnt = (int)gcur[bin] - bin * BCAP;
    if (cnt > BCAP) cnt = BCAP;
    const unsigned* __restrict__ bp = binned + (size_t)bin * BCAP;
    const int wave = t >> 6, l = t & 63;

    for (int e0 = wave * 4; e0 < cnt; e0 += 32) {
        int4 pks = *(const int4*)(bp + e0);          // 16B-aligned, within capacity
        unsigned pkj[4] = {(unsigned)pks.x, (unsigned)pks.y, (unsigned)pks.z, (unsigned)pks.w};
        #pragma unroll
        for (int j = 0; j < 4; ++j) {
            if (e0 + j < cnt) {
                unsigned pk = pkj[j];
                int srcn = (int)(pk & 0x1FFFFu);
                int dn   = (int)((pk >> 17) & (BINSZ - 1));
                float f0 = b2f(xb[(size_t)srcn * DIM + l]);
                float f1 = b2f(xb[(size_t)srcn * DIM + 64 + l]);
                atomicAdd(&acc[dn * DIM + l], f0);        // bank l%32: 2-way, free
                atomicAdd(&acc[dn * DIM + 64 + l], f1);
            }
        }
    }
    __syncthreads();

    #pragma unroll
    for (int i = 0; i < 32; ++i) {
        int flat = i * 512 + t;
        int node = node0 + (flat >> 7);
        if (node < N) h0b[(size_t)node * DIM + (flat & 127)] = f2b(acc[flat]);
    }
}

// ---------------------------------------------------------------- MFMA GEMM + bias + BN-stats (+optional input BN+ReLU)
template<bool APPLY_BN, bool OUT_BF16>
__global__ __launch_bounds__(1024)
void gemm_mfma(const unsigned short* __restrict__ A, const float* __restrict__ Wf,
               const float* __restrict__ bias, const float* __restrict__ ss,
               void* __restrict__ outp, float* __restrict__ stats, int N)
{
    __shared__ unsigned short sWT[128 * 128];  // swizzled W^T (bf16), 32 KB
    __shared__ float red[256];
    const int tid = threadIdx.x;

    #pragma unroll
    for (int i = 0; i < 4; ++i) {
        int idx = (i * 1024 + tid) * 4;
        float4 w = *(const float4*)&Wf[idx];
        int k = idx >> 7, n0 = idx & 127;
        sWT[(n0 + 0) * 128 + (k ^ (((n0 + 0) & 7) << 3))] = f2b(w.x);
        sWT[(n0 + 1) * 128 + (k ^ (((n0 + 1) & 7) << 3))] = f2b(w.y);
        sWT[(n0 + 2) * 128 + (k ^ (((n0 + 2) & 7) << 3))] = f2b(w.z);
        sWT[(n0 + 3) * 128 + (k ^ (((n0 + 3) & 7) << 3))] = f2b(w.w);
    }
    if (tid < 256) red[tid] = 0.f;
    __syncthreads();

    const int lane = tid & 63;
    const int wave = tid >> 6;
    const int r0   = blockIdx.x * 256 + wave * 16;
    const int rl   = lane & 15;
    const int kg   = lane >> 4;
    int rr = r0 + rl;
    int rclamp = rr < N ? rr : N - 1;
    const unsigned short* arow = A + (size_t)rclamp * DIM + kg * 8;

    f32x4 acc[8];
    #pragma unroll
    for (int nt = 0; nt < 8; ++nt) acc[nt] = (f32x4)(0.f);

    #pragma unroll
    for (int kk = 0; kk < 128; kk += 32) {
        bf16x8 a8 = *(const bf16x8*)(arow + kk);
        if (APPLY_BN) {
            const float* sc = ss + kk + kg * 8;
            const float* sh = sc + DIM;
            bf16x8 tt;
            #pragma unroll
            for (int j = 0; j < 8; ++j) {
                float f = b2f((unsigned short)a8[j]) * sc[j] + sh[j];
                tt[j] = (short)f2b(fmaxf(f, 0.f));
            }
            a8 = tt;
        }
        const int ks = kk + kg * 8;
        #pragma unroll
        for (int nt = 0; nt < 8; ++nt) {
            int n = nt * 16 + rl;
            bf16x8 b8 = *(const bf16x8*)&sWT[n * 128 + (ks ^ ((n & 7) << 3))];
            acc[nt] = __builtin_amdgcn_mfma_f32_16x16x32_bf16(a8, b8, acc[nt], 0, 0, 0);
        }
    }

    const int orow0 = r0 + kg * 4;
    #pragma unroll
    for (int nt = 0; nt < 8; ++nt) {
        int n = nt * 16 + rl;
        float bb = bias[n];
        float ls = 0.f, ls2 = 0.f;
        #pragma unroll
        for (int j = 0; j < 4; ++j) {
            int r = orow0 + j;
            if (r < N) {
                float v = acc[nt][j] + bb;
                if (OUT_BF16) ((unsigned short*)outp)[(size_t)r * DIM + n] = f2b(v);
                else          ((float*)outp)[(size_t)r * DIM + n] = v;
                ls += v; ls2 += v * v;
            }
        }
        ls  += __shfl_xor(ls, 16);  ls  += __shfl_xor(ls, 32);
        ls2 += __shfl_xor(ls2, 16); ls2 += __shfl_xor(ls2, 32);
        if (kg == 0) { atomicAdd(&red[n], ls); atomicAdd(&red[128 + n], ls2); }
    }
    __syncthreads();
    if (tid < 256) atomicAdd(&stats[tid], red[tid]);
}

// ---------------------------------------------------------------- BN finalize
__global__ void bn_finalize(const float* __restrict__ stats, const float* __restrict__ gamma,
                            const float* __restrict__ beta, float* __restrict__ ss, float invN)
{
    int c = threadIdx.x;
    float mu  = stats[c] * invN;
    float var = stats[DIM + c] * invN - mu * mu;
    var = fmaxf(var, 0.f);
    float sc = gamma[c] * rsqrtf(var + 1e-5f);
    ss[c]       = sc;
    ss[DIM + c] = beta[c] - mu * sc;
}

// ---------------------------------------------------------------- final BN+ReLU in place on d_out (fp32)
__global__ __launch_bounds__(256)
void bn_relu_out(float* __restrict__ h, const float* __restrict__ ss, int n4)
{
    int i = blockIdx.x * 256 + threadIdx.x;
    if (i >= n4) return;
    int c = (i * 4) & 127;
    float4 sc = *(const float4*)&ss[c];
    float4 sh = *(const float4*)&ss[DIM + c];
    float4 v = ((float4*)h)[i];
    v.x = fmaxf(v.x * sc.x + sh.x, 0.f);
    v.y = fmaxf(v.y * sc.y + sh.y, 0.f);
    v.z = fmaxf(v.z * sc.z + sh.z, 0.f);
    v.w = fmaxf(v.w * sc.w + sh.w, 0.f);
    ((float4*)h)[i] = v;
}

// ----------------------------------------------------------------
extern "C" void kernel_launch(void* const* d_in, const int* in_sizes, int n_in,
                              void* d_out, int out_size, void* d_ws, size_t ws_size,
                              hipStream_t stream) {
    const float* x    = (const float*)d_in[0];
    const int*   ei   = (const int*)  d_in[1];
    const float* W1   = (const float*)d_in[2];
    const float* b1   = (const float*)d_in[3];
    const float* g1   = (const float*)d_in[4];
    const float* be1  = (const float*)d_in[5];
    const float* W2   = (const float*)d_in[6];
    const float* b2   = (const float*)d_in[7];
    const float* g2   = (const float*)d_in[8];
    const float* be2  = (const float*)d_in[9];
    const float* epsp = (const float*)d_in[10];
    float* out = (float*)d_out;

    const int N = in_sizes[0] / DIM;   // 100000
    const int E = in_sizes[1] / 2;     // 1600000
    const int* src = ei;
    const int* dst = ei + E;
    const int nbins = (N + BINSZ - 1) >> BINSHIFT;   // 782

    // workspace layout (~76.8 MB):
    //   xb   [N*128 ushort]   25.6 MB
    //   h0b  [N*128 ushort]   25.6 MB
    //   regC [N*128 ushort]   25.6 MB : binned[nbins*BCAP u32] (8 MB) then overlaid by h1b
    //   tail: gcur[1024 u32], stats1/stats2/ss1/ss2 [256 f each]
    unsigned short* xb  = (unsigned short*)d_ws;
    unsigned short* h0b = xb + (size_t)N * DIM;
    unsigned short* regC = h0b + (size_t)N * DIM;
    unsigned* binned = (unsigned*)regC;
    unsigned short* h1b = regC;
    unsigned* gcur = (unsigned*)(regC + (size_t)N * DIM);
    float* stats1 = (float*)(gcur + 1024);
    float* stats2 = stats1 + 256;
    float* ss1    = stats2 + 256;
    float* ss2    = ss1 + 256;

    hipMemsetAsync(stats1, 0, 512 * sizeof(float), stream);
    init_gcur<<<(nbins + 255) / 256, 256, 0, stream>>>(gcur, nbins);

    const int n8 = N * DIM / 8;
    x_to_bf16<<<(n8 + 255) / 256, 256, 0, stream>>>(x, xb, n8);

    bin_edges<<<(E + EPB - 1) / EPB, 1024, 0, stream>>>(src, dst, gcur, binned, E, nbins);
    bin_agg<<<nbins, 512, 0, stream>>>(xb, epsp, gcur, binned, h0b, N);

    const int gblocks = (N + 255) / 256;
    gemm_mfma<false, true><<<gblocks, 1024, 0, stream>>>(h0b, W1, b1, nullptr, h1b, stats1, N);
    bn_finalize<<<1, DIM, 0, stream>>>(stats1, g1, be1, ss1, 1.0f / (float)N);
    gemm_mfma<true, false><<<gblocks, 1024, 0, stream>>>(h1b, W2, b2, ss1, out, stats2, N);
    bn_finalize<<<1, DIM, 0, stream>>>(stats2, g2, be2, ss2, 1.0f / (float)N);
    const int n4 = N * DIM / 4;
    bn_relu_out<<<(n4 + 255) / 256, 256, 0, stream>>>(out, ss2, n4);
}

// Round 5
// 191.493 us; speedup vs baseline: 7.5799x; 7.5799x over previous
//
#include <hip/hip_runtime.h>

#define DIM 128
#define BINSHIFT 7
#define BINSZ 128          // nodes per bin
#define BCAP 2560          // edges capacity per bin: Poisson(2048)+11sigma
#define EPB 8192           // edges per binning block

typedef __attribute__((ext_vector_type(8))) short bf16x8;
typedef __attribute__((ext_vector_type(4))) float f32x4;

__device__ inline unsigned short f2b(float f) {
    unsigned u = __builtin_bit_cast(unsigned, f);
    unsigned r = (u + 0x7FFFu + ((u >> 16) & 1u)) >> 16;
    return (unsigned short)r;
}
__device__ inline float b2f(unsigned short h) {
    unsigned u = ((unsigned)h) << 16;
    return __builtin_bit_cast(float, u);
}

// ---------------------------------------------------------------- gcur[b] = b*BCAP
__global__ __launch_bounds__(256)
void init_gcur(unsigned* __restrict__ gcur, int nbins)
{
    int i = blockIdx.x * 256 + threadIdx.x;
    if (i < nbins) gcur[i] = (unsigned)i * BCAP;
}

// ---------------------------------------------------------------- x (fp32) -> xb (bf16)
__global__ __launch_bounds__(256)
void x_to_bf16(const float* __restrict__ x, unsigned short* __restrict__ xb, int n8)
{
    int i = blockIdx.x * 256 + threadIdx.x;
    if (i >= n8) return;
    float4 a = ((const float4*)x)[i * 2];
    float4 b = ((const float4*)x)[i * 2 + 1];
    bf16x8 o;
    o[0] = (short)f2b(a.x); o[1] = (short)f2b(a.y); o[2] = (short)f2b(a.z); o[3] = (short)f2b(a.w);
    o[4] = (short)f2b(b.x); o[5] = (short)f2b(b.y); o[6] = (short)f2b(b.z); o[7] = (short)f2b(b.w);
    ((bf16x8*)xb)[i] = o;
}

// ---------------------------------------------------------------- bin edges by dst>>7, packed (dstlow<<17)|src
__global__ __launch_bounds__(1024)
void bin_edges(const int* __restrict__ src, const int* __restrict__ dst,
               unsigned* __restrict__ gcur, unsigned* __restrict__ binned,
               int E, int nbins)
{
    __shared__ unsigned hist[1024];
    __shared__ unsigned base[1024];
    const int t = threadIdx.x;
    const long long bb = (long long)blockIdx.x * EPB;
    if (t < nbins) hist[t] = 0;
    __syncthreads();

    unsigned pk[8], pos[8];
    int bn[8];
    bool ok[8];
    #pragma unroll
    for (int i = 0; i < 8; ++i) {
        long long idx = bb + i * 1024 + t;
        ok[i] = idx < E;
        if (ok[i]) {
            int s = src[idx], d = dst[idx];
            pk[i] = ((unsigned)(d & (BINSZ - 1)) << 17) | (unsigned)s;
            bn[i] = d >> BINSHIFT;
            pos[i] = atomicAdd(&hist[bn[i]], 1u);
        }
    }
    __syncthreads();
    if (t < nbins) base[t] = atomicAdd(&gcur[t], hist[t]);
    __syncthreads();
    #pragma unroll
    for (int i = 0; i < 8; ++i) {
        if (ok[i]) {
            unsigned off = base[bn[i]] + pos[i];
            if (off < (unsigned)(bn[i] + 1) * BCAP) binned[off] = pk[i];
        }
    }
}

// ---------------------------------------------------------------- per-bin aggregate v2:
// LDS counting-sort of the bin's edges by node, then register-accumulated gather.
// 512 threads: 16 lanes per node (8 channels each), 32 nodes per sweep, 4 sweeps.
__global__ __launch_bounds__(512)
void bin_agg2(const unsigned short* __restrict__ xb, const float* __restrict__ epsp,
              const unsigned* __restrict__ gcur, const unsigned* __restrict__ binned,
              unsigned short* __restrict__ h0b, int N)
{
    __shared__ unsigned sorted[BCAP];   // 10 KB: src ids grouped by node
    __shared__ unsigned hist[BINSZ];
    __shared__ unsigned base[BINSZ];
    __shared__ unsigned cur[BINSZ];
    const int t = threadIdx.x;
    const int bin = blockIdx.x;
    const int node0 = bin << BINSHIFT;

    if (t < BINSZ) hist[t] = 0;
    __syncthreads();

    int cnt = (int)gcur[bin] - bin * BCAP;
    if (cnt > BCAP) cnt = BCAP;
    const unsigned* __restrict__ bp = binned + (size_t)bin * BCAP;

    // pass 1: histogram by node-in-bin
    for (int i = t; i < cnt; i += 512)
        atomicAdd(&hist[(bp[i] >> 17) & (BINSZ - 1)], 1u);
    __syncthreads();
    // exclusive scan (tiny, serial)
    if (t == 0) {
        unsigned run = 0;
        for (int i = 0; i < BINSZ; ++i) { base[i] = run; run += hist[i]; }
    }
    __syncthreads();
    if (t < BINSZ) cur[t] = base[t];
    __syncthreads();
    // pass 2: place src ids grouped by node (bp re-read from L2)
    for (int i = t; i < cnt; i += 512) {
        unsigned p = bp[i];
        unsigned pos = atomicAdd(&cur[(p >> 17) & (BINSZ - 1)], 1u);
        sorted[pos] = p & 0x1FFFFu;
    }
    __syncthreads();

    // gather: register accumulation, 4-way unrolled independent loads
    const float e = 1.0f + epsp[0];
    const int g = (t & 15) * 8;     // channel offset
    const int slot = t >> 4;        // 0..31
    #pragma unroll
    for (int sw = 0; sw < 4; ++sw) {
        int dn = sw * 32 + slot;
        int node = node0 + dn;
        if (node < N) {
            bf16x8 v0 = *(const bf16x8*)(xb + (size_t)node * DIM + g);
            float acc[8];
            #pragma unroll
            for (int q = 0; q < 8; ++q) acc[q] = e * b2f((unsigned short)v0[q]);
            const int b0 = (int)base[dn], hn = (int)hist[dn];
            int j = 0;
            for (; j + 4 <= hn; j += 4) {
                unsigned s0 = sorted[b0 + j + 0];
                unsigned s1 = sorted[b0 + j + 1];
                unsigned s2 = sorted[b0 + j + 2];
                unsigned s3 = sorted[b0 + j + 3];
                bf16x8 r0 = *(const bf16x8*)(xb + (size_t)s0 * DIM + g);
                bf16x8 r1 = *(const bf16x8*)(xb + (size_t)s1 * DIM + g);
                bf16x8 r2 = *(const bf16x8*)(xb + (size_t)s2 * DIM + g);
                bf16x8 r3 = *(const bf16x8*)(xb + (size_t)s3 * DIM + g);
                #pragma unroll
                for (int q = 0; q < 8; ++q)
                    acc[q] += b2f((unsigned short)r0[q]) + b2f((unsigned short)r1[q])
                            + b2f((unsigned short)r2[q]) + b2f((unsigned short)r3[q]);
            }
            for (; j < hn; ++j) {
                unsigned s0 = sorted[b0 + j];
                bf16x8 r0 = *(const bf16x8*)(xb + (size_t)s0 * DIM + g);
                #pragma unroll
                for (int q = 0; q < 8; ++q) acc[q] += b2f((unsigned short)r0[q]);
            }
            bf16x8 o;
            #pragma unroll
            for (int q = 0; q < 8; ++q) o[q] = (short)f2b(acc[q]);
            *(bf16x8*)(h0b + (size_t)node * DIM + g) = o;
        }
    }
}

// ---------------------------------------------------------------- MFMA GEMM + bias + BN-stats (+optional input BN+ReLU)
template<bool APPLY_BN, bool OUT_BF16>
__global__ __launch_bounds__(1024)
void gemm_mfma(const unsigned short* __restrict__ A, const float* __restrict__ Wf,
               const float* __restrict__ bias, const float* __restrict__ ss,
               void* __restrict__ outp, float* __restrict__ stats, int N)
{
    __shared__ unsigned short sWT[128 * 128];  // swizzled W^T (bf16), 32 KB
    __shared__ float red[256];
    const int tid = threadIdx.x;

    #pragma unroll
    for (int i = 0; i < 4; ++i) {
        int idx = (i * 1024 + tid) * 4;
        float4 w = *(const float4*)&Wf[idx];
        int k = idx >> 7, n0 = idx & 127;
        sWT[(n0 + 0) * 128 + (k ^ (((n0 + 0) & 7) << 3))] = f2b(w.x);
        sWT[(n0 + 1) * 128 + (k ^ (((n0 + 1) & 7) << 3))] = f2b(w.y);
        sWT[(n0 + 2) * 128 + (k ^ (((n0 + 2) & 7) << 3))] = f2b(w.z);
        sWT[(n0 + 3) * 128 + (k ^ (((n0 + 3) & 7) << 3))] = f2b(w.w);
    }
    if (tid < 256) red[tid] = 0.f;
    __syncthreads();

    const int lane = tid & 63;
    const int wave = tid >> 6;
    const int r0   = blockIdx.x * 256 + wave * 16;
    const int rl   = lane & 15;
    const int kg   = lane >> 4;
    int rr = r0 + rl;
    int rclamp = rr < N ? rr : N - 1;
    const unsigned short* arow = A + (size_t)rclamp * DIM + kg * 8;

    f32x4 acc[8];
    #pragma unroll
    for (int nt = 0; nt < 8; ++nt) acc[nt] = (f32x4)(0.f);

    #pragma unroll
    for (int kk = 0; kk < 128; kk += 32) {
        bf16x8 a8 = *(const bf16x8*)(arow + kk);
        if (APPLY_BN) {
            const float* sc = ss + kk + kg * 8;
            const float* sh = sc + DIM;
            bf16x8 tt;
            #pragma unroll
            for (int j = 0; j < 8; ++j) {
                float f = b2f((unsigned short)a8[j]) * sc[j] + sh[j];
                tt[j] = (short)f2b(fmaxf(f, 0.f));
            }
            a8 = tt;
        }
        const int ks = kk + kg * 8;
        #pragma unroll
        for (int nt = 0; nt < 8; ++nt) {
            int n = nt * 16 + rl;
            bf16x8 b8 = *(const bf16x8*)&sWT[n * 128 + (ks ^ ((n & 7) << 3))];
            acc[nt] = __builtin_amdgcn_mfma_f32_16x16x32_bf16(a8, b8, acc[nt], 0, 0, 0);
        }
    }

    const int orow0 = r0 + kg * 4;
    #pragma unroll
    for (int nt = 0; nt < 8; ++nt) {
        int n = nt * 16 + rl;
        float bb = bias[n];
        float ls = 0.f, ls2 = 0.f;
        #pragma unroll
        for (int j = 0; j < 4; ++j) {
            int r = orow0 + j;
            if (r < N) {
                float v = acc[nt][j] + bb;
                if (OUT_BF16) ((unsigned short*)outp)[(size_t)r * DIM + n] = f2b(v);
                else          ((float*)outp)[(size_t)r * DIM + n] = v;
                ls += v; ls2 += v * v;
            }
        }
        ls  += __shfl_xor(ls, 16);  ls  += __shfl_xor(ls, 32);
        ls2 += __shfl_xor(ls2, 16); ls2 += __shfl_xor(ls2, 32);
        if (kg == 0) { atomicAdd(&red[n], ls); atomicAdd(&red[128 + n], ls2); }
    }
    __syncthreads();
    if (tid < 256) atomicAdd(&stats[tid], red[tid]);
}

// ---------------------------------------------------------------- BN finalize
__global__ void bn_finalize(const float* __restrict__ stats, const float* __restrict__ gamma,
                            const float* __restrict__ beta, float* __restrict__ ss, float invN)
{
    int c = threadIdx.x;
    float mu  = stats[c] * invN;
    float var = stats[DIM + c] * invN - mu * mu;
    var = fmaxf(var, 0.f);
    float sc = gamma[c] * rsqrtf(var + 1e-5f);
    ss[c]       = sc;
    ss[DIM + c] = beta[c] - mu * sc;
}

// ---------------------------------------------------------------- final BN+ReLU in place on d_out (fp32)
__global__ __launch_bounds__(256)
void bn_relu_out(float* __restrict__ h, const float* __restrict__ ss, int n4)
{
    int i = blockIdx.x * 256 + threadIdx.x;
    if (i >= n4) return;
    int c = (i * 4) & 127;
    float4 sc = *(const float4*)&ss[c];
    float4 sh = *(const float4*)&ss[DIM + c];
    float4 v = ((float4*)h)[i];
    v.x = fmaxf(v.x * sc.x + sh.x, 0.f);
    v.y = fmaxf(v.y * sc.y + sh.y, 0.f);
    v.z = fmaxf(v.z * sc.z + sh.z, 0.f);
    v.w = fmaxf(v.w * sc.w + sh.w, 0.f);
    ((float4*)h)[i] = v;
}

// ----------------------------------------------------------------
extern "C" void kernel_launch(void* const* d_in, const int* in_sizes, int n_in,
                              void* d_out, int out_size, void* d_ws, size_t ws_size,
                              hipStream_t stream) {
    const float* x    = (const float*)d_in[0];
    const int*   ei   = (const int*)  d_in[1];
    const float* W1   = (const float*)d_in[2];
    const float* b1   = (const float*)d_in[3];
    const float* g1   = (const float*)d_in[4];
    const float* be1  = (const float*)d_in[5];
    const float* W2   = (const float*)d_in[6];
    const float* b2   = (const float*)d_in[7];
    const float* g2   = (const float*)d_in[8];
    const float* be2  = (const float*)d_in[9];
    const float* epsp = (const float*)d_in[10];
    float* out = (float*)d_out;

    const int N = in_sizes[0] / DIM;   // 100000
    const int E = in_sizes[1] / 2;     // 1600000
    const int* src = ei;
    const int* dst = ei + E;
    const int nbins = (N + BINSZ - 1) >> BINSHIFT;   // 782

    // workspace layout (~76.8 MB):
    //   xb   [N*128 ushort]   25.6 MB
    //   h0b  [N*128 ushort]   25.6 MB
    //   regC [N*128 ushort]   25.6 MB : binned[nbins*BCAP u32] (8 MB) then overlaid by h1b
    //   tail: gcur[1024 u32], stats1/stats2/ss1/ss2 [256 f each]
    unsigned short* xb  = (unsigned short*)d_ws;
    unsigned short* h0b = xb + (size_t)N * DIM;
    unsigned short* regC = h0b + (size_t)N * DIM;
    unsigned* binned = (unsigned*)regC;
    unsigned short* h1b = regC;
    unsigned* gcur = (unsigned*)(regC + (size_t)N * DIM);
    float* stats1 = (float*)(gcur + 1024);
    float* stats2 = stats1 + 256;
    float* ss1    = stats2 + 256;
    float* ss2    = ss1 + 256;

    hipMemsetAsync(stats1, 0, 512 * sizeof(float), stream);
    init_gcur<<<(nbins + 255) / 256, 256, 0, stream>>>(gcur, nbins);

    const int n8 = N * DIM / 8;
    x_to_bf16<<<(n8 + 255) / 256, 256, 0, stream>>>(x, xb, n8);

    bin_edges<<<(E + EPB - 1) / EPB, 1024, 0, stream>>>(src, dst, gcur, binned, E, nbins);
    bin_agg2<<<nbins, 512, 0, stream>>>(xb, epsp, gcur, binned, h0b, N);

    const int gblocks = (N + 255) / 256;
    gemm_mfma<false, true><<<gblocks, 1024, 0, stream>>>(h0b, W1, b1, nullptr, h1b, stats1, N);
    bn_finalize<<<1, DIM, 0, stream>>>(stats1, g1, be1, ss1, 1.0f / (float)N);
    gemm_mfma<true, false><<<gblocks, 1024, 0, stream>>>(h1b, W2, b2, ss1, out, stats2, N);
    bn_finalize<<<1, DIM, 0, stream>>>(stats2, g2, be2, ss2, 1.0f / (float)N);
    const int n4 = N * DIM / 4;
    bn_relu_out<<<(n4 + 255) / 256, 256, 0, stream>>>(out, ss2, n4);
}